// Round 5
// baseline (118.894 us; speedup 1.0000x reference)
//
#include <hip/hip_runtime.h>

#define NBATCH 256
#define NFILT  128

typedef __attribute__((ext_vector_type(8))) short bf16x8;
typedef __attribute__((ext_vector_type(4))) float f32x4;

__device__ __forceinline__ unsigned short f2b(float f) {
    unsigned u = __float_as_uint(f);
    u = (u + 0x7fffu + ((u >> 16) & 1u)) >> 16;
    return (unsigned short)u;
}
__device__ __forceinline__ float b2f(unsigned short h) {
    return __uint_as_float(((unsigned)h) << 16);
}
__device__ __forceinline__ void async16(const void* g, void* l) {
    __builtin_amdgcn_global_load_lds((const __attribute__((address_space(1))) unsigned int*)g,
                                     (__attribute__((address_space(3))) unsigned int*)l, 16, 0, 0);
}

// ---------------- fused prep kernel ----------------
// blocks [0,2048): W0 ; [2048,6144): W1 ; [6144,10240): W2 ; [10240,14336): x
// W tiling: granule per (rg, kstep): [kseg(4)][l15(16)][j(8)]; kstep = f*NCS + cs.
__global__ void prep_all(const float* __restrict__ x,
                         const float* __restrict__ W0,
                         const float* __restrict__ W1,
                         const float* __restrict__ W2,
                         unsigned short* __restrict__ x0t,
                         unsigned short* __restrict__ x0f,
                         unsigned short* __restrict__ Wp0,
                         unsigned short* __restrict__ Wp1,
                         unsigned short* __restrict__ Wp2)
{
    const int bid = blockIdx.x, tid = threadIdx.x;
    if (bid < 10240) {
        const float* W; unsigned short* Wp; int CLOG, KLOG, idx;
        if (bid < 2048)      { W = W0; Wp = Wp0; CLOG = 6; KLOG = 12; idx = bid * 256 + tid; }
        else if (bid < 6144) { W = W1; Wp = Wp1; CLOG = 7; KLOG = 13; idx = (bid - 2048) * 256 + tid; }
        else                 { W = W2; Wp = Wp2; CLOG = 7; KLOG = 13; idx = (bid - 6144) * 256 + tid; }
        int o = idx >> KLOG, k = idx & ((1 << KLOG) - 1);
        int f = k >> CLOG, c = k & ((1 << CLOG) - 1);
        int rg = o >> 4, l15 = o & 15;
        int cs = c >> 5, kseg = (c >> 3) & 3, j = c & 7;
        int NCS = 1 << (CLOG - 5);
        int NK = 64 * NCS;
        int kstep = f * NCS + cs;
        size_t dst = (((size_t)rg * NK + kstep) * 64 + kseg * 16 + l15) * 8 + j;
        Wp[dst] = f2b(W[idx]);
    } else {
        int idx = (bid - 10240) * 256 + tid;
        int b = idx >> 12, r = idx & 4095, f = r >> 6, e = r & 63;
        unsigned short v = f2b(x[idx]);
        x0f[b * 4096 + f * 64 + e] = v;   // [b][f][e]
        x0t[b * 4096 + e * 64 + f] = v;   // [b][e][f]  (layer-0 B source, plain)
    }
}

// ---------------- per-layer GEMM kernel ----------------
// grid 256 = 8 rg (16 o-rows) x 32 sg (8 samples); 512 thr, wave w = sample sg*8+w.
// P[o, e] = sum_f x0[f,e] * (sum_c W[o,f,c] * xk[c,e]); B granules field-invariant,
// resident in VGPRs; A streams global->VGPR (L1/L2; W slice per XCD is L2-resident).
template <int CL, bool LAST>
__global__ __launch_bounds__(512) void layer_k(
    const unsigned short* __restrict__ Wp,    // pre-tiled A, rg-sliced
    const unsigned short* __restrict__ Bsrc,  // [b][e][c] rows of CL*2 bytes
    const unsigned short* __restrict__ x0f,   // [b][f][e]
    const float* __restrict__ Wa_l,
    unsigned short* __restrict__ xknext,      // [b][e][o] rows of 256B
    float* __restrict__ ybuf)                 // [256][8] this layer
{
    constexpr int NCS = CL / 32;
    constexpr int NK  = 64 * NCS;
    constexpr int NG  = NK / 4;
    extern __shared__ char sm[];
    const int bid = blockIdx.x, tid = threadIdx.x;
    const int rg = bid & 7, sg = bid >> 3;
    const int lane = tid & 63, w = tid >> 6;
    const int l15 = lane & 15, kseg = lane >> 4;
    const int b = sg * 8 + w;

    // stage this wave's sample x0f (8KB) into its own LDS region
    {
        const char* src = (const char*)x0f + (size_t)b * 8192 + lane * 16;
        char* dst = sm + w * 8192;
#pragma unroll
        for (int i = 0; i < 8; ++i) async16(src + i * 1024, dst + i * 1024);
    }

    // B granules: load once, keep resident (field-invariant)
    bf16x8 bq[NCS][4];
    const char* Bb = (const char*)Bsrc + (size_t)b * (CL * 128) + kseg * 16;
#pragma unroll
    for (int cs = 0; cs < NCS; ++cs)
#pragma unroll
        for (int nt = 0; nt < 4; ++nt)
            bq[cs][nt] = *(const bf16x8*)(Bb + (nt * 16 + l15) * (CL * 2) + cs * 64);

    // A stream: 4-slot ring, depth-2 prefetch, static slots
    const char* Ag = (const char*)Wp + ((size_t)rg * NK) * 1024 + (kseg * 16 + l15) * 16;
    bf16x8 aq[4];
    aq[0] = *(const bf16x8*)(Ag);
    aq[1] = *(const bf16x8*)(Ag + 1024);

    __syncthreads();

    const unsigned short* XF = (const unsigned short*)(sm + w * 8192);
    const f32x4 ZERO = {0.f, 0.f, 0.f, 0.f};
    f32x4 acc[4], accf[4];
#pragma unroll
    for (int nt = 0; nt < 4; ++nt) acc[nt] = ZERO;

    for (int g = 0; g < NG; ++g) {
        const size_t k0 = (size_t)g * 4;
        float sA[4], sB[4];
        if (NCS == 4) {
#pragma unroll
            for (int nt = 0; nt < 4; ++nt) sA[nt] = b2f(XF[g * 64 + nt * 16 + l15]);
        } else {
#pragma unroll
            for (int nt = 0; nt < 4; ++nt) {
                sA[nt] = b2f(XF[(2 * g) * 64 + nt * 16 + l15]);
                sB[nt] = b2f(XF[(2 * g + 1) * 64 + nt * 16 + l15]);
            }
        }
        // s=0
        aq[2] = *(const bf16x8*)(Ag + (k0 + 2) * 1024);
#pragma unroll
        for (int nt = 0; nt < 4; ++nt)
            accf[nt] = __builtin_amdgcn_mfma_f32_16x16x32_bf16(aq[0], bq[0][nt], ZERO, 0, 0, 0);
        // s=1
        aq[3] = *(const bf16x8*)(Ag + (k0 + 3) * 1024);
#pragma unroll
        for (int nt = 0; nt < 4; ++nt)
            accf[nt] = __builtin_amdgcn_mfma_f32_16x16x32_bf16(aq[1], bq[1 & (NCS - 1)][nt], accf[nt], 0, 0, 0);
        if (NCS == 2) {
#pragma unroll
            for (int nt = 0; nt < 4; ++nt) {
                const f32x4 sv = {sA[nt], sA[nt], sA[nt], sA[nt]};
                acc[nt] += accf[nt] * sv;
            }
        }
        // s=2
        aq[0] = *(const bf16x8*)(Ag + (k0 + 4) * 1024);
#pragma unroll
        for (int nt = 0; nt < 4; ++nt)
            accf[nt] = __builtin_amdgcn_mfma_f32_16x16x32_bf16(aq[2], bq[2 & (NCS - 1)][nt],
                                                               (NCS == 2) ? ZERO : accf[nt], 0, 0, 0);
        // s=3
        aq[1] = *(const bf16x8*)(Ag + (k0 + 5) * 1024);
#pragma unroll
        for (int nt = 0; nt < 4; ++nt)
            accf[nt] = __builtin_amdgcn_mfma_f32_16x16x32_bf16(aq[3], bq[3 & (NCS - 1)][nt], accf[nt], 0, 0, 0);
        {
            const float* sf = (NCS == 2) ? sB : sA;
#pragma unroll
            for (int nt = 0; nt < 4; ++nt) {
                const f32x4 sv = {sf[nt], sf[nt], sf[nt], sf[nt]};
                acc[nt] += accf[nt] * sv;
            }
        }
    }

    // epilogue: relu, y-partial, xk write
    const float4 wa = *(const float4*)(Wa_l + rg * 16 + kseg * 4);
    float ypart = 0.f;
#pragma unroll
    for (int nt = 0; nt < 4; ++nt) {
        f32x4 v = acc[nt];
        v.x = fmaxf(v.x, 0.f); v.y = fmaxf(v.y, 0.f);
        v.z = fmaxf(v.z, 0.f); v.w = fmaxf(v.w, 0.f);
        ypart = fmaf(wa.x, v.x, ypart);
        ypart = fmaf(wa.y, v.y, ypart);
        ypart = fmaf(wa.z, v.z, ypart);
        ypart = fmaf(wa.w, v.w, ypart);
        if (!LAST) {
            unsigned lo = (unsigned)f2b(v.x) | ((unsigned)f2b(v.y) << 16);
            unsigned hi = (unsigned)f2b(v.z) | ((unsigned)f2b(v.w) << 16);
            *(uint2*)((char*)xknext + (size_t)b * 16384 + (nt * 16 + l15) * 256
                      + (rg * 16 + kseg * 4) * 2) = make_uint2(lo, hi);
        }
    }
#pragma unroll
    for (int off = 32; off >= 1; off >>= 1)
        ypart += __shfl_down(ypart, off, 64);
    if (lane == 0) ybuf[b * 8 + rg] = ypart;
}

__global__ void finalize_k(const float* __restrict__ ybuf, float* __restrict__ y) {
    const int b = threadIdx.x;
    float s = 0.f;
#pragma unroll
    for (int l = 0; l < 3; ++l)
#pragma unroll
        for (int r = 0; r < 8; ++r)
            s += ybuf[l * 2048 + b * 8 + r];
    y[b] = s;
}

extern "C" void kernel_launch(void* const* d_in, const int* in_sizes, int n_in,
                              void* d_out, int out_size, void* d_ws, size_t ws_size,
                              hipStream_t stream) {
    const float* x  = (const float*)d_in[0];
    const float* W0 = (const float*)d_in[1];
    const float* W1 = (const float*)d_in[2];
    const float* W2 = (const float*)d_in[3];
    const float* Wa = (const float*)d_in[4];
    float* y = (float*)d_out;

    char* ws = (char*)d_ws;
    unsigned short* Wp0  = (unsigned short*)(ws + 0x000000);   // 1MB (+pad)
    unsigned short* Wp1  = (unsigned short*)(ws + 0x110000);   // 2MB (+pad)
    unsigned short* Wp2  = (unsigned short*)(ws + 0x320000);   // 2MB (+pad)
    unsigned short* x0t  = (unsigned short*)(ws + 0x530000);   // 2MB
    unsigned short* x0f  = (unsigned short*)(ws + 0x730000);   // 2MB
    unsigned short* xkA  = (unsigned short*)(ws + 0x930000);   // 4MB
    unsigned short* xkB  = (unsigned short*)(ws + 0xD30000);   // 4MB
    float*          ybuf = (float*)(ws + 0x1130000);           // 24KB

    hipLaunchKernelGGL(prep_all, dim3(14336), dim3(256), 0, stream,
                       x, W0, W1, W2, x0t, x0f, Wp0, Wp1, Wp2);

    hipFuncSetAttribute((const void*)layer_k<64, false>,
                        hipFuncAttributeMaxDynamicSharedMemorySize, 65536);
    hipFuncSetAttribute((const void*)layer_k<128, false>,
                        hipFuncAttributeMaxDynamicSharedMemorySize, 65536);
    hipFuncSetAttribute((const void*)layer_k<128, true>,
                        hipFuncAttributeMaxDynamicSharedMemorySize, 65536);

    hipLaunchKernelGGL((layer_k<64, false>), dim3(256), dim3(512), 65536, stream,
                       Wp0, x0t, x0f, Wa + 0, xkA, ybuf + 0);
    hipLaunchKernelGGL((layer_k<128, false>), dim3(256), dim3(512), 65536, stream,
                       Wp1, xkA, x0f, Wa + 128, xkB, ybuf + 2048);
    hipLaunchKernelGGL((layer_k<128, true>), dim3(256), dim3(512), 65536, stream,
                       Wp2, xkB, x0f, Wa + 256, xkA, ybuf + 4096);

    hipLaunchKernelGGL(finalize_k, dim3(1), dim3(256), 0, stream, ybuf, y);
}

// Round 6
// 100.290 us; speedup vs baseline: 1.1855x; 1.1855x over previous
//
#include <hip/hip_runtime.h>

#define NBATCH 256

typedef __attribute__((ext_vector_type(8))) short bf16x8;
typedef __attribute__((ext_vector_type(4))) float f32x4;

__device__ __forceinline__ unsigned short f2b(float f) {
    unsigned u = __float_as_uint(f);
    u = (u + 0x7fffu + ((u >> 16) & 1u)) >> 16;
    return (unsigned short)u;
}
__device__ __forceinline__ float b2f(unsigned short h) {
    return __uint_as_float(((unsigned)h) << 16);
}
__device__ __forceinline__ void async16(const void* g, void* l) {
    __builtin_amdgcn_global_load_lds((const __attribute__((address_space(1))) unsigned int*)g,
                                     (__attribute__((address_space(3))) unsigned int*)l, 16, 0, 0);
}

// ---------------- fused prep kernel (x4 vectorized) ----------------
// blocks [0,512): W0 ; [512,1536): W1 ; [1536,2560): W2 ; [2560,3584): x
// W tiling: granule per (rg, kstep): [kseg(4)][l15(16)][j(8)]; kstep = f*NCS + cs.
__global__ void prep_all(const float* __restrict__ x,
                         const float* __restrict__ W0,
                         const float* __restrict__ W1,
                         const float* __restrict__ W2,
                         unsigned short* __restrict__ x0t,
                         unsigned short* __restrict__ x0f,
                         unsigned short* __restrict__ Wp0,
                         unsigned short* __restrict__ Wp1,
                         unsigned short* __restrict__ Wp2)
{
    const int bid = blockIdx.x, tid = threadIdx.x;
    if (bid < 2560) {
        const float* W; unsigned short* Wp; int CLOG, KLOG, lbid;
        if (bid < 512)       { W = W0; Wp = Wp0; CLOG = 6; KLOG = 12; lbid = bid; }
        else if (bid < 1536) { W = W1; Wp = Wp1; CLOG = 7; KLOG = 13; lbid = bid - 512; }
        else                 { W = W2; Wp = Wp2; CLOG = 7; KLOG = 13; lbid = bid - 1536; }
        const int base = (lbid * 256 + tid) * 4;   // 4 consecutive k, same o
        int o = base >> KLOG, k = base & ((1 << KLOG) - 1);
        int f = k >> CLOG, c = k & ((1 << CLOG) - 1);
        int rg = o >> 4, l15 = o & 15;
        int cs = c >> 5, kseg = (c >> 3) & 3, j = c & 7;   // j aligned to 4
        int NCS = 1 << (CLOG - 5);
        int NK = 64 * NCS;
        int kstep = f * NCS + cs;
        size_t dst = (((size_t)rg * NK + kstep) * 64 + kseg * 16 + l15) * 8 + j;
        const float4 wv = *(const float4*)(W + base);
        ushort4 ov = make_ushort4(f2b(wv.x), f2b(wv.y), f2b(wv.z), f2b(wv.w));
        *(ushort4*)(Wp + dst) = ov;
    } else {
        const int base = ((bid - 2560) * 256 + tid) * 4;   // 4 consecutive e
        int b = base >> 12, r = base & 4095, f = r >> 6, e0 = r & 63;
        const float4 xv = *(const float4*)(x + base);
        ushort4 v = make_ushort4(f2b(xv.x), f2b(xv.y), f2b(xv.z), f2b(xv.w));
        *(ushort4*)(x0f + b * 4096 + f * 64 + e0) = v;     // [b][f][e]
        x0t[b * 4096 + (e0 + 0) * 64 + f] = v.x;           // [b][e][f]
        x0t[b * 4096 + (e0 + 1) * 64 + f] = v.y;
        x0t[b * 4096 + (e0 + 2) * 64 + f] = v.z;
        x0t[b * 4096 + (e0 + 3) * 64 + f] = v.w;
    }
}

// ---------------- per-layer GEMM kernel ----------------
// grid 256 = 8 rg (16 o-rows) x 32 sg (8 samples); 512 thr; wave = one sample.
// A (W rg-slice) double-buffered in LDS, 16-kstep chunks, shared by all 8 waves.
// B (xk granules) VGPR-resident, pinned with empty asm. x0f per-wave in LDS.
template <int CL, bool LAST>
__global__ __launch_bounds__(512, 1) void layer_k(
    const unsigned short* __restrict__ Wp,    // pre-tiled A, rg-sliced
    const unsigned short* __restrict__ Bsrc,  // [b][e][c] rows of CL*2 bytes
    const unsigned short* __restrict__ x0f,   // [b][f][e]
    const float* __restrict__ Wa_l,
    unsigned short* __restrict__ xknext,      // [b][e][o] rows of 256B
    float* __restrict__ ybuf)                 // [256][8] this layer
{
    constexpr int NCS = CL / 32;
    constexpr int NK  = 64 * NCS;
    constexpr int NCH = NK / 16;
    constexpr int NFOLD = 16 / NCS;
    extern __shared__ char sm[];
    char* smA = sm;                  // 2 x 16 KB A chunks
    char* smX = sm + 32768;          // 8 x 8 KB x0f per wave
    const int bid = blockIdx.x, tid = threadIdx.x;
    const int rg = bid & 7, sg = bid >> 3;
    const int lane = tid & 63, w = tid >> 6;
    const int l15 = lane & 15, kseg = lane >> 4;
    const int b = sg * 8 + w;

    // stage this wave's sample x0f (8KB)
    {
        const char* src = (const char*)x0f + (size_t)b * 8192 + lane * 16;
        char* dst = smX + w * 8192;
#pragma unroll
        for (int i = 0; i < 8; ++i) async16(src + i * 1024, dst + i * 1024);
    }

    // B granules: load once, keep VGPR-resident (field-invariant)
    bf16x8 bq[NCS][4];
    {
        const char* Bb = (const char*)Bsrc + (size_t)b * (CL * 128) + kseg * 16;
#pragma unroll
        for (int cs = 0; cs < NCS; ++cs)
#pragma unroll
            for (int nt = 0; nt < 4; ++nt)
                bq[cs][nt] = *(const bf16x8*)(Bb + (nt * 16 + l15) * (CL * 2) + cs * 64);
    }

    const char* Ab = (const char*)Wp + (size_t)rg * NK * 1024;
    auto stage = [&](int ch, int buf) {
        const char* src = Ab + (size_t)ch * 16384 + w * 2048 + lane * 16;
        char* dst = smA + buf * 16384 + w * 2048;   // wave-uniform dst
        async16(src, dst);
        async16(src + 1024, dst + 1024);
    };
    stage(0, 0);
    __syncthreads();   // x0f + chunk0 + bq all complete

    const unsigned short* XF = (const unsigned short*)(smX + w * 8192);
    const f32x4 ZERO = {0.f, 0.f, 0.f, 0.f};
    f32x4 acc[4], accf[4];
#pragma unroll
    for (int nt = 0; nt < 4; ++nt) acc[nt] = ZERO;

    for (int ch = 0; ch < NCH; ++ch) {
        const int cur = ch & 1;
        if (ch + 1 < NCH) stage(ch + 1, cur ^ 1);
        // pin bq in registers (prevents the compiler sinking B loads into the loop)
#pragma unroll
        for (int cs = 0; cs < NCS; ++cs)
            asm volatile("" :: "v"(bq[cs][0]), "v"(bq[cs][1]), "v"(bq[cs][2]), "v"(bq[cs][3]));
        const char* Abuf = smA + cur * 16384 + lane * 16;
#pragma unroll
        for (int gi = 0; gi < NFOLD; ++gi) {
            const int fg = ch * NFOLD + gi;
            const float sv0 = b2f(XF[fg * 64 + l15]);
            const float sv1 = b2f(XF[fg * 64 + 16 + l15]);
            const float sv2 = b2f(XF[fg * 64 + 32 + l15]);
            const float sv3 = b2f(XF[fg * 64 + 48 + l15]);
#pragma unroll
            for (int cs = 0; cs < NCS; ++cs) {
                const bf16x8 a = *(const bf16x8*)(Abuf + (gi * NCS + cs) * 1024);
#pragma unroll
                for (int nt = 0; nt < 4; ++nt)
                    accf[nt] = __builtin_amdgcn_mfma_f32_16x16x32_bf16(
                        a, bq[cs][nt], (cs == 0) ? ZERO : accf[nt], 0, 0, 0);
            }
            acc[0] += accf[0] * sv0;
            acc[1] += accf[1] * sv1;
            acc[2] += accf[2] * sv2;
            acc[3] += accf[3] * sv3;
        }
        __syncthreads();
    }

    // epilogue: relu, y-partial, xk write
    const float4 wa = *(const float4*)(Wa_l + rg * 16 + kseg * 4);
    float ypart = 0.f;
#pragma unroll
    for (int nt = 0; nt < 4; ++nt) {
        f32x4 v = acc[nt];
        v.x = fmaxf(v.x, 0.f); v.y = fmaxf(v.y, 0.f);
        v.z = fmaxf(v.z, 0.f); v.w = fmaxf(v.w, 0.f);
        ypart = fmaf(wa.x, v.x, ypart);
        ypart = fmaf(wa.y, v.y, ypart);
        ypart = fmaf(wa.z, v.z, ypart);
        ypart = fmaf(wa.w, v.w, ypart);
        if (!LAST) {
            unsigned lo = (unsigned)f2b(v.x) | ((unsigned)f2b(v.y) << 16);
            unsigned hi = (unsigned)f2b(v.z) | ((unsigned)f2b(v.w) << 16);
            *(uint2*)((char*)xknext + (size_t)b * 16384 + (nt * 16 + l15) * 256
                      + (rg * 16 + kseg * 4) * 2) = make_uint2(lo, hi);
        }
    }
#pragma unroll
    for (int off = 32; off >= 1; off >>= 1)
        ypart += __shfl_down(ypart, off, 64);
    if (lane == 0) ybuf[b * 8 + rg] = ypart;
}

__global__ void finalize_k(const float* __restrict__ ybuf, float* __restrict__ y) {
    const int b = threadIdx.x;
    float s = 0.f;
#pragma unroll
    for (int l = 0; l < 3; ++l)
#pragma unroll
        for (int r = 0; r < 8; ++r)
            s += ybuf[l * 2048 + b * 8 + r];
    y[b] = s;
}

extern "C" void kernel_launch(void* const* d_in, const int* in_sizes, int n_in,
                              void* d_out, int out_size, void* d_ws, size_t ws_size,
                              hipStream_t stream) {
    const float* x  = (const float*)d_in[0];
    const float* W0 = (const float*)d_in[1];
    const float* W1 = (const float*)d_in[2];
    const float* W2 = (const float*)d_in[3];
    const float* Wa = (const float*)d_in[4];
    float* y = (float*)d_out;

    char* ws = (char*)d_ws;
    unsigned short* Wp0  = (unsigned short*)(ws + 0x000000);   // 1MB (+pad)
    unsigned short* Wp1  = (unsigned short*)(ws + 0x110000);   // 2MB (+pad)
    unsigned short* Wp2  = (unsigned short*)(ws + 0x320000);   // 2MB (+pad)
    unsigned short* x0t  = (unsigned short*)(ws + 0x530000);   // 2MB
    unsigned short* x0f  = (unsigned short*)(ws + 0x730000);   // 2MB
    unsigned short* xkA  = (unsigned short*)(ws + 0x930000);   // 4MB
    unsigned short* xkB  = (unsigned short*)(ws + 0xD30000);   // 4MB
    float*          ybuf = (float*)(ws + 0x1130000);           // 24KB

    hipLaunchKernelGGL(prep_all, dim3(3584), dim3(256), 0, stream,
                       x, W0, W1, W2, x0t, x0f, Wp0, Wp1, Wp2);

    hipFuncSetAttribute((const void*)layer_k<64, false>,
                        hipFuncAttributeMaxDynamicSharedMemorySize, 98304);
    hipFuncSetAttribute((const void*)layer_k<128, false>,
                        hipFuncAttributeMaxDynamicSharedMemorySize, 98304);
    hipFuncSetAttribute((const void*)layer_k<128, true>,
                        hipFuncAttributeMaxDynamicSharedMemorySize, 98304);

    hipLaunchKernelGGL((layer_k<64, false>), dim3(256), dim3(512), 98304, stream,
                       Wp0, x0t, x0f, Wa + 0, xkA, ybuf + 0);
    hipLaunchKernelGGL((layer_k<128, false>), dim3(256), dim3(512), 98304, stream,
                       Wp1, xkA, x0f, Wa + 128, xkB, ybuf + 2048);
    hipLaunchKernelGGL((layer_k<128, true>), dim3(256), dim3(512), 98304, stream,
                       Wp2, xkB, x0f, Wa + 256, xkA, ybuf + 4096);

    hipLaunchKernelGGL(finalize_k, dim3(1), dim3(256), 0, stream, ybuf, y);
}